// Round 1
// baseline (689.722 us; speedup 1.0000x reference)
//
#include <hip/hip_runtime.h>
#include <hip/hip_bf16.h>

typedef unsigned short u16;
typedef __attribute__((ext_vector_type(8))) short bf16x8;
typedef __attribute__((ext_vector_type(4))) float f32x4;
typedef __attribute__((ext_vector_type(8))) unsigned short ushort8;

#define FEAT 1024
#define NOUT 16384
#define EPS 1e-6f

#define GLOBAL_AS __attribute__((address_space(1)))
#define LDS_AS __attribute__((address_space(3)))

__device__ __forceinline__ void load16_to_lds(const void* g, void* l) {
    __builtin_amdgcn_global_load_lds((const GLOBAL_AS void*)g, (LDS_AS void*)l, 16, 0, 0);
}

__device__ __forceinline__ u16 f32_to_bf16_bits(float f) {
    __hip_bfloat16 h = __float2bfloat16(f);
    return *reinterpret_cast<u16*>(&h);
}

// Build W[o][k] = A[a][k]*B[b][k]*C[c][k] in bf16, o = a*512 + b*16 + c.
// One thread per 8 consecutive k. Total threads: 16384 * 128.
__global__ void wbuild_kernel(const float* __restrict__ w, u16* __restrict__ Wb) {
    const int t  = blockIdx.x * 256 + threadIdx.x;
    const int o  = t >> 7;
    const int k0 = (t & 127) << 3;
    const int ai = o >> 9;
    const int bi = (o >> 4) & 31;
    const int ci = o & 15;
    const float* A = w + ai * FEAT + k0;
    const float* B = w + (32 + bi) * FEAT + k0;
    const float* C = w + (64 + ci) * FEAT + k0;
    ushort8 r;
#pragma unroll
    for (int j = 0; j < 8; ++j) {
        r[j] = f32_to_bf16_bits(A[j] * B[j] * C[j]);
    }
    *reinterpret_cast<ushort8*>(Wb + (size_t)t * 8) = r;
}

// Cast x fp32 -> bf16, 8 elements per thread.
__global__ void xcast_kernel(const float* __restrict__ x, u16* __restrict__ Xb) {
    const int t = blockIdx.x * 256 + threadIdx.x;
    const float4* xv = reinterpret_cast<const float4*>(x) + (size_t)t * 2;
    const float4 f0 = xv[0];
    const float4 f1 = xv[1];
    float vals[8] = {f0.x, f0.y, f0.z, f0.w, f1.x, f1.y, f1.z, f1.w};
    ushort8 r;
#pragma unroll
    for (int j = 0; j < 8; ++j) r[j] = f32_to_bf16_bits(vals[j]);
    *reinterpret_cast<ushort8*>(Xb + (size_t)t * 8) = r;
}

// 128x128 tile bf16 GEMM: Y[m][n] = sum_k Xb[m][k] * Wb[n][k]  (fp32 out)
// 256 threads = 4 waves in 2x2; each wave computes 64x64 via 4x4 fragments
// of v_mfma_f32_16x16x32_bf16. BK=32, staged via global_load_lds (16B).
__global__ __launch_bounds__(256) void gemm_kernel(const u16* __restrict__ Xb,
                                                   const u16* __restrict__ Wb,
                                                   float* __restrict__ Y) {
    __shared__ u16 Xs[128 * 32];
    __shared__ u16 Ws[128 * 32];
    const int tid  = threadIdx.x;
    const int lane = tid & 63;
    const int wave = tid >> 6;
    const int wm = wave >> 1;    // wave row (0..1)
    const int wn = wave & 1;     // wave col (0..1)
    const int brow = blockIdx.y * 128;
    const int bcol = blockIdx.x * 128;
    const int fr = lane & 15;    // fragment row index (m or n within 16)
    const int kg = lane >> 4;    // k-group (0..3), 8 elements each

    f32x4 acc[4][4] = {};

    // staging: element-group e (16B) -> LDS row e>>2, colgroup e&3
    const int r0  = tid >> 2;
    const int cg0 = tid & 3;
    const u16* gX0 = Xb + (size_t)(brow + r0) * FEAT + cg0 * 8;
    const u16* gX1 = Xb + (size_t)(brow + r0 + 64) * FEAT + cg0 * 8;
    const u16* gW0 = Wb + (size_t)(bcol + r0) * FEAT + cg0 * 8;
    const u16* gW1 = Wb + (size_t)(bcol + r0 + 64) * FEAT + cg0 * 8;
    // wave-uniform LDS bases (global_load_lds writes base + lane*16)
    u16* lX0 = Xs + (size_t)(tid & ~63) * 8;
    u16* lX1 = Xs + (size_t)((tid & ~63) + 256) * 8;
    u16* lW0 = Ws + (size_t)(tid & ~63) * 8;
    u16* lW1 = Ws + (size_t)((tid & ~63) + 256) * 8;

    for (int k0 = 0; k0 < FEAT; k0 += 32) {
        __syncthreads();
        load16_to_lds(gX0 + k0, lX0);
        load16_to_lds(gX1 + k0, lX1);
        load16_to_lds(gW0 + k0, lW0);
        load16_to_lds(gW1 + k0, lW1);
        __syncthreads();

        bf16x8 a[4], b[4];
#pragma unroll
        for (int i = 0; i < 4; ++i)
            a[i] = *reinterpret_cast<const bf16x8*>(Xs + (wm * 64 + i * 16 + fr) * 32 + kg * 8);
#pragma unroll
        for (int j = 0; j < 4; ++j)
            b[j] = *reinterpret_cast<const bf16x8*>(Ws + (wn * 64 + j * 16 + fr) * 32 + kg * 8);
#pragma unroll
        for (int i = 0; i < 4; ++i)
#pragma unroll
            for (int j = 0; j < 4; ++j)
                acc[i][j] = __builtin_amdgcn_mfma_f32_16x16x32_bf16(a[i], b[j], acc[i][j], 0, 0, 0);
    }

    // epilogue: C/D layout col = lane&15, row = (lane>>4)*4 + reg
#pragma unroll
    for (int i = 0; i < 4; ++i) {
        const int row0 = brow + wm * 64 + i * 16 + kg * 4;
#pragma unroll
        for (int r = 0; r < 4; ++r) {
            float* yrow = Y + (size_t)(row0 + r) * NOUT + bcol + wn * 64 + fr;
#pragma unroll
            for (int j = 0; j < 4; ++j)
                yrow[j * 16] = acc[i][j][r];
        }
    }
}

// In-place RMS norm over rows of 16384 fp32. One block (1024 threads) per row.
__global__ __launch_bounds__(1024) void rmsnorm_kernel(float* __restrict__ Y) {
    float* p = Y + (size_t)blockIdx.x * NOUT;
    const int tid = threadIdx.x;
    float4 v[4];
    float ss = 0.f;
#pragma unroll
    for (int i = 0; i < 4; ++i) {
        v[i] = reinterpret_cast<float4*>(p)[tid + i * 1024];
        ss += v[i].x * v[i].x + v[i].y * v[i].y + v[i].z * v[i].z + v[i].w * v[i].w;
    }
#pragma unroll
    for (int off = 1; off < 64; off <<= 1) ss += __shfl_xor(ss, off, 64);
    __shared__ float wss[16];
    if ((tid & 63) == 0) wss[tid >> 6] = ss;
    __syncthreads();
    float tot = 0.f;
#pragma unroll
    for (int i = 0; i < 16; ++i) tot += wss[i];
    const float scale = rsqrtf(tot * (1.0f / (float)NOUT) + EPS);
#pragma unroll
    for (int i = 0; i < 4; ++i) {
        v[i].x *= scale; v[i].y *= scale; v[i].z *= scale; v[i].w *= scale;
        reinterpret_cast<float4*>(p)[tid + i * 1024] = v[i];
    }
}

extern "C" void kernel_launch(void* const* d_in, const int* in_sizes, int n_in,
                              void* d_out, int out_size, void* d_ws, size_t ws_size,
                              hipStream_t stream) {
    const float* x = (const float*)d_in[0];   // (4,2048,1024) fp32 = (8192,1024)
    const float* w = (const float*)d_in[1];   // (80,1024) fp32
    float* out = (float*)d_out;               // (8192,16384) fp32

    const int M = in_sizes[0] / FEAT;         // 8192

    u16* Wb = (u16*)d_ws;                                        // 16384*1024 bf16 = 32 MiB
    u16* Xb = (u16*)((char*)d_ws + (size_t)NOUT * FEAT * 2);     // M*1024 bf16 = 16 MiB

    // 1) build bf16 W from low-rank factors
    wbuild_kernel<<<(NOUT * (FEAT / 8)) / 256, 256, 0, stream>>>(w, Wb);
    // 2) cast x to bf16
    xcast_kernel<<<(M * FEAT / 8) / 256, 256, 0, stream>>>(x, Xb);
    // 3) GEMM y = x @ W^T (fp32 out)
    dim3 ggrid(NOUT / 128, M / 128);
    gemm_kernel<<<ggrid, 256, 0, stream>>>(Xb, Wb, out);
    // 4) in-place RMS norm per row
    rmsnorm_kernel<<<M, 1024, 0, stream>>>(out);
}

// Round 2
// 589.476 us; speedup vs baseline: 1.1701x; 1.1701x over previous
//
#include <hip/hip_runtime.h>
#include <hip/hip_bf16.h>

typedef unsigned short u16;
typedef __attribute__((ext_vector_type(8))) short bf16x8;
typedef __attribute__((ext_vector_type(4))) float f32x4;
typedef __attribute__((ext_vector_type(8))) unsigned short ushort8;

#define FEAT 1024
#define NOUT 16384
#define EPS 1e-6f

#define GLOBAL_AS __attribute__((address_space(1)))
#define LDS_AS __attribute__((address_space(3)))

__device__ __forceinline__ void load16_to_lds(const void* g, void* l) {
    __builtin_amdgcn_global_load_lds((const GLOBAL_AS void*)g, (LDS_AS void*)l, 16, 0, 0);
}

__device__ __forceinline__ u16 f32_to_bf16_bits(float f) {
    __hip_bfloat16 h = __float2bfloat16(f);
    return *reinterpret_cast<u16*>(&h);
}

__device__ __forceinline__ float bf16_bits_to_f32(u16 b) {
    unsigned u = ((unsigned)b) << 16;
    float f;
    __builtin_memcpy(&f, &u, 4);
    return f;
}

// Build W[o][k] = A[a][k]*B[b][k]*C[c][k] in bf16, o = a*512 + b*16 + c.
__global__ void wbuild_kernel(const float* __restrict__ w, u16* __restrict__ Wb) {
    const int t  = blockIdx.x * 256 + threadIdx.x;
    const int o  = t >> 7;
    const int k0 = (t & 127) << 3;
    const int ai = o >> 9;
    const int bi = (o >> 4) & 31;
    const int ci = o & 15;
    const float* A = w + ai * FEAT + k0;
    const float* B = w + (32 + bi) * FEAT + k0;
    const float* C = w + (64 + ci) * FEAT + k0;
    ushort8 r;
#pragma unroll
    for (int j = 0; j < 8; ++j) {
        r[j] = f32_to_bf16_bits(A[j] * B[j] * C[j]);
    }
    *reinterpret_cast<ushort8*>(Wb + (size_t)t * 8) = r;
}

// Cast x fp32 -> bf16, 8 elements per thread.
__global__ void xcast_kernel(const float* __restrict__ x, u16* __restrict__ Xb) {
    const int t = blockIdx.x * 256 + threadIdx.x;
    const float4* xv = reinterpret_cast<const float4*>(x) + (size_t)t * 2;
    const float4 f0 = xv[0];
    const float4 f1 = xv[1];
    float vals[8] = {f0.x, f0.y, f0.z, f0.w, f1.x, f1.y, f1.z, f1.w};
    ushort8 r;
#pragma unroll
    for (int j = 0; j < 8; ++j) r[j] = f32_to_bf16_bits(vals[j]);
    *reinterpret_cast<ushort8*>(Xb + (size_t)t * 8) = r;
}

// 128x128 tile bf16 GEMM, BK=64, XOR-swizzled LDS (16B chunk index ^ row&7).
// Emits bf16 y (row stride 32768 u16 = first half of each 64KB fp32 out row)
// plus per-(row, colblock) partial sum-of-squares (fp32, deterministic).
__global__ __launch_bounds__(256) void gemm_kernel(const u16* __restrict__ Xb,
                                                   const u16* __restrict__ Wb,
                                                   u16* __restrict__ Y,
                                                   float* __restrict__ Psum) {
    __shared__ u16 Xs[128 * 64];
    __shared__ u16 Ws[128 * 64];
    __shared__ float sspart[128][2];

    // bijective XCD swizzle: 8192 blocks, 8 XCDs, 1024 per XCD
    const int bid = blockIdx.x;
    const int swz = (bid & 7) * 1024 + (bid >> 3);
    const int bx = swz & 127;          // col block (fastest within XCD)
    const int by = swz >> 7;           // row block
    const int brow = by * 128;
    const int bcol = bx * 128;

    const int tid  = threadIdx.x;
    const int lane = tid & 63;
    const int wave = tid >> 6;
    const int wm = wave >> 1;
    const int wn = wave & 1;
    const int fr = lane & 15;
    const int kg = lane >> 4;

    f32x4 acc[4][4] = {};

    // staging: 1024 chunks of 16B per operand tile; thread handles chunks
    // c = i*256 + tid. LDS layout linear; global source pre-swizzled.
    const u16* gx[4];
    const u16* gw[4];
#pragma unroll
    for (int i = 0; i < 4; ++i) {
        const int c = i * 256 + tid;
        const int row = c >> 3;
        const int slot = c & 7;
        const int kc = slot ^ (row & 7);      // logical k-chunk stored at this slot
        gx[i] = Xb + (size_t)(brow + row) * FEAT + kc * 8;
        gw[i] = Wb + (size_t)(bcol + row) * FEAT + kc * 8;
    }
    const int wbase = tid & ~63;

    for (int k0 = 0; k0 < FEAT; k0 += 64) {
        __syncthreads();
#pragma unroll
        for (int i = 0; i < 4; ++i) {
            load16_to_lds(gx[i] + k0, Xs + (size_t)(i * 256 + wbase) * 8);
            load16_to_lds(gw[i] + k0, Ws + (size_t)(i * 256 + wbase) * 8);
        }
        __syncthreads();

#pragma unroll
        for (int kk = 0; kk < 2; ++kk) {
            const int sa = (((kk * 4 + kg) ^ (fr & 7)) << 3);  // swizzled slot*8 (u16)
            bf16x8 a[4], b[4];
#pragma unroll
            for (int i = 0; i < 4; ++i)
                a[i] = *reinterpret_cast<const bf16x8*>(Xs + (wm * 64 + i * 16 + fr) * 64 + sa);
#pragma unroll
            for (int j = 0; j < 4; ++j)
                b[j] = *reinterpret_cast<const bf16x8*>(Ws + (wn * 64 + j * 16 + fr) * 64 + sa);
#pragma unroll
            for (int i = 0; i < 4; ++i)
#pragma unroll
                for (int j = 0; j < 4; ++j)
                    acc[i][j] = __builtin_amdgcn_mfma_f32_16x16x32_bf16(a[i], b[j], acc[i][j], 0, 0, 0);
        }
    }

    // epilogue: bf16 y + per-row partial sum of squares (from fp32 acc)
    const int colbase = bcol + wn * 64 + fr;
#pragma unroll
    for (int i = 0; i < 4; ++i) {
#pragma unroll
        for (int r = 0; r < 4; ++r) {
            const int lrow = wm * 64 + i * 16 + kg * 4 + r;
            u16* yrow = Y + (size_t)(brow + lrow) * 32768 + colbase;
            float s = 0.f;
#pragma unroll
            for (int j = 0; j < 4; ++j) {
                const float v = acc[i][j][r];
                s += v * v;
                yrow[j * 16] = f32_to_bf16_bits(v);
            }
            // reduce over the 16 lanes (fr) of this kg group
            s += __shfl_xor(s, 1, 64);
            s += __shfl_xor(s, 2, 64);
            s += __shfl_xor(s, 4, 64);
            s += __shfl_xor(s, 8, 64);
            if (fr == 0) sspart[lrow][wn] = s;
        }
    }
    __syncthreads();
    if (tid < 128)
        Psum[(size_t)(brow + tid) * 128 + bx] = sspart[tid][0] + sspart[tid][1];
}

// Per-row scale: read bf16 y row + 128 partials, write fp32 normalized row
// in-place over the same 64KB row slot (reads drained before writes).
__global__ __launch_bounds__(1024) void scale_kernel(const u16* __restrict__ Y,
                                                     const float* __restrict__ Psum,
                                                     float* __restrict__ out) {
    const int row = blockIdx.x;
    const int tid = threadIdx.x;
    const ushort8* yr = reinterpret_cast<const ushort8*>(Y + (size_t)row * 32768);
    const ushort8 v0 = yr[2 * tid];
    const ushort8 v1 = yr[2 * tid + 1];

    __shared__ float scs;
    if (tid < 64) {
        float s = Psum[(size_t)row * 128 + tid] + Psum[(size_t)row * 128 + 64 + tid];
        s += __shfl_xor(s, 1, 64);
        s += __shfl_xor(s, 2, 64);
        s += __shfl_xor(s, 4, 64);
        s += __shfl_xor(s, 8, 64);
        s += __shfl_xor(s, 16, 64);
        s += __shfl_xor(s, 32, 64);
        if (tid == 0) scs = rsqrtf(s * (1.0f / (float)NOUT) + EPS);
    }
    // all loads must have READ memory before any thread overwrites the row
    asm volatile("s_waitcnt vmcnt(0)" ::: "memory");
    __syncthreads();
    const float sc = scs;

    float4* orow = reinterpret_cast<float4*>(out + (size_t)row * NOUT) + tid * 4;
    float4 o0, o1, o2, o3;
    o0.x = bf16_bits_to_f32(v0[0]) * sc; o0.y = bf16_bits_to_f32(v0[1]) * sc;
    o0.z = bf16_bits_to_f32(v0[2]) * sc; o0.w = bf16_bits_to_f32(v0[3]) * sc;
    o1.x = bf16_bits_to_f32(v0[4]) * sc; o1.y = bf16_bits_to_f32(v0[5]) * sc;
    o1.z = bf16_bits_to_f32(v0[6]) * sc; o1.w = bf16_bits_to_f32(v0[7]) * sc;
    o2.x = bf16_bits_to_f32(v1[0]) * sc; o2.y = bf16_bits_to_f32(v1[1]) * sc;
    o2.z = bf16_bits_to_f32(v1[2]) * sc; o2.w = bf16_bits_to_f32(v1[3]) * sc;
    o3.x = bf16_bits_to_f32(v1[4]) * sc; o3.y = bf16_bits_to_f32(v1[5]) * sc;
    o3.z = bf16_bits_to_f32(v1[6]) * sc; o3.w = bf16_bits_to_f32(v1[7]) * sc;
    orow[0] = o0; orow[1] = o1; orow[2] = o2; orow[3] = o3;
}

extern "C" void kernel_launch(void* const* d_in, const int* in_sizes, int n_in,
                              void* d_out, int out_size, void* d_ws, size_t ws_size,
                              hipStream_t stream) {
    const float* x = (const float*)d_in[0];   // (8192,1024) fp32
    const float* w = (const float*)d_in[1];   // (80,1024) fp32
    float* out = (float*)d_out;               // (8192,16384) fp32

    const int M = in_sizes[0] / FEAT;         // 8192

    u16* Wb = (u16*)d_ws;                                          // 32 MiB
    u16* Xb = (u16*)((char*)d_ws + (size_t)NOUT * FEAT * 2);       // 16 MiB
    float* Psum = (float*)((char*)d_ws + (size_t)(NOUT + M) * FEAT * 2); // 4 MiB

    // bf16 y lives in the first 32KB of each 64KB output row slot
    u16* Y = (u16*)d_out;

    wbuild_kernel<<<(NOUT * (FEAT / 8)) / 256, 256, 0, stream>>>(w, Wb);
    xcast_kernel<<<(M * FEAT / 8) / 256, 256, 0, stream>>>(x, Xb);

    const int nblk = (NOUT / 128) * (M / 128);   // 8192
    gemm_kernel<<<nblk, 256, 0, stream>>>(Xb, Wb, Y, Psum);

    scale_kernel<<<M, 1024, 0, stream>>>(Y, Psum, out);
}

// Round 3
// 483.322 us; speedup vs baseline: 1.4270x; 1.2196x over previous
//
#include <hip/hip_runtime.h>
#include <hip/hip_bf16.h>

typedef unsigned short u16;
typedef __attribute__((ext_vector_type(8))) short bf16x8;
typedef __attribute__((ext_vector_type(4))) float f32x4;
typedef __attribute__((ext_vector_type(8))) unsigned short ushort8;

#define FEAT 1024
#define NOUT 16384
#define EPS 1e-6f
#define NT 16            // K-tiles of 64

#define GLOBAL_AS __attribute__((address_space(1)))
#define LDS_AS __attribute__((address_space(3)))

__device__ __forceinline__ void load16_to_lds(const u16* g, u16* l) {
    __builtin_amdgcn_global_load_lds((const GLOBAL_AS void*)g, (LDS_AS void*)l, 16, 0, 0);
}

__device__ __forceinline__ u16 f32_to_bf16_bits(float f) {
    __hip_bfloat16 h = __float2bfloat16(f);
    return *reinterpret_cast<u16*>(&h);
}

__device__ __forceinline__ float bf16_bits_to_f32(u16 b) {
    unsigned u = ((unsigned)b) << 16;
    float f;
    __builtin_memcpy(&f, &u, 4);
    return f;
}

// Build W[o][k] = A[a][k]*B[b][k]*C[c][k] in bf16, o = a*512 + b*16 + c.
__global__ void wbuild_kernel(const float* __restrict__ w, u16* __restrict__ Wb) {
    const int t  = blockIdx.x * 256 + threadIdx.x;
    const int o  = t >> 7;
    const int k0 = (t & 127) << 3;
    const int ai = o >> 9;
    const int bi = (o >> 4) & 31;
    const int ci = o & 15;
    const float* A = w + ai * FEAT + k0;
    const float* B = w + (32 + bi) * FEAT + k0;
    const float* C = w + (64 + ci) * FEAT + k0;
    ushort8 r;
#pragma unroll
    for (int j = 0; j < 8; ++j) r[j] = f32_to_bf16_bits(A[j] * B[j] * C[j]);
    *reinterpret_cast<ushort8*>(Wb + (size_t)t * 8) = r;
}

__global__ void xcast_kernel(const float* __restrict__ x, u16* __restrict__ Xb) {
    const int t = blockIdx.x * 256 + threadIdx.x;
    const float4* xv = reinterpret_cast<const float4*>(x) + (size_t)t * 2;
    const float4 f0 = xv[0];
    const float4 f1 = xv[1];
    float vals[8] = {f0.x, f0.y, f0.z, f0.w, f1.x, f1.y, f1.z, f1.w};
    ushort8 r;
#pragma unroll
    for (int j = 0; j < 8; ++j) r[j] = f32_to_bf16_bits(vals[j]);
    *reinterpret_cast<ushort8*>(Xb + (size_t)t * 8) = r;
}

// ---------------- 256x256 8-phase pipelined GEMM ----------------
// 512 threads = 8 waves (2 M-halves x 4 N-quarters), wave tile 128x64.
// LDS: 2 buffers x (A 256x64 + B 256x64) bf16 = 128 KiB, stored as
// [buf][op][khalf][256 rows][32 cols], 16B chunks XOR-swizzled:
// phys_slot = logical_chunk ^ ((row>>1)&3)  -> conflict-free ds_read_b128.
// Staging rotation (1 half-tile = 2 global_load_lds/thread per phase):
//   t.p1: A(t+1) k1 -> nbuf   t.p2: B(t+1) k0 -> nbuf
//   t.p3: B(t+1) k1 -> nbuf   t.p4: A(t+2) k0 -> buf (k0 dead after p2)
// One vmcnt(2) per K-tile at p4 (3 half-tiles ago issued = landed).

#define LDSOFF(buf, isB, kh) (((buf) << 15) + ((isB) << 14) + ((kh) << 13))

#define STAGE(isB, tt, kh, buf) do {                                          \
    const u16* g = ((isB) ? gB : gA) + (size_t)(tt) * 64 + (kh) * 32 + w * 32768; \
    u16* l = lds + LDSOFF(buf, isB, kh) + w * 1024;                           \
    load16_to_lds(g, l);                                                      \
    load16_to_lds(g + 16384, l + 512);                                        \
} while (0)

#define RD_A(dst, mi, ks, buf) dst = *reinterpret_cast<const bf16x8*>(        \
    lds + LDSOFF(buf, 0, ks) + (wm * 128 + (mi) * 16 + fr) * 32 + ((kg ^ ((fr >> 1) & 3)) << 3))
#define RD_B(dst, nj, ks, buf) dst = *reinterpret_cast<const bf16x8*>(        \
    lds + LDSOFF(buf, 1, ks) + (wn * 64 + (nj) * 16 + fr) * 32 + ((kg ^ ((fr >> 1) & 3)) << 3))

#define PHASE_SYNC() do {                                                     \
    __builtin_amdgcn_sched_barrier(0);                                        \
    __builtin_amdgcn_s_barrier();                                             \
    asm volatile("s_waitcnt lgkmcnt(0)" ::: "memory");                        \
    __builtin_amdgcn_sched_barrier(0);                                        \
} while (0)

#define MFMA_Q(mibase) do {                                                   \
    __builtin_amdgcn_s_setprio(1);                                            \
    _Pragma("unroll")                                                         \
    for (int mi = 0; mi < 4; ++mi) {                                          \
        acc[(mibase)+mi][0] = __builtin_amdgcn_mfma_f32_16x16x32_bf16(a[mi], b[0], acc[(mibase)+mi][0], 0, 0, 0); \
        acc[(mibase)+mi][1] = __builtin_amdgcn_mfma_f32_16x16x32_bf16(a[mi], b[1], acc[(mibase)+mi][1], 0, 0, 0); \
        acc[(mibase)+mi][2] = __builtin_amdgcn_mfma_f32_16x16x32_bf16(a[mi], b[2], acc[(mibase)+mi][2], 0, 0, 0); \
        acc[(mibase)+mi][3] = __builtin_amdgcn_mfma_f32_16x16x32_bf16(a[mi], b[3], acc[(mibase)+mi][3], 0, 0, 0); \
    }                                                                         \
    __builtin_amdgcn_s_setprio(0);                                            \
    __builtin_amdgcn_sched_barrier(0);                                        \
    __builtin_amdgcn_s_barrier();                                             \
} while (0)

#define TILE_BODY(t, buf, nbuf) do {                                          \
    /* phase 1: compute (m0-3, k0); stage A(t+1) k1 */                        \
    RD_A(a[0], 0, 0, buf); RD_A(a[1], 1, 0, buf);                             \
    RD_A(a[2], 2, 0, buf); RD_A(a[3], 3, 0, buf);                             \
    RD_B(b[0], 0, 0, buf); RD_B(b[1], 1, 0, buf);                             \
    RD_B(b[2], 2, 0, buf); RD_B(b[3], 3, 0, buf);                             \
    if ((t) < NT - 1) STAGE(0, (t) + 1, 1, nbuf);                             \
    PHASE_SYNC();                                                             \
    MFMA_Q(0);                                                                \
    /* phase 2: compute (m4-7, k0); stage B(t+1) k0 */                        \
    RD_A(a[0], 4, 0, buf); RD_A(a[1], 5, 0, buf);                             \
    RD_A(a[2], 6, 0, buf); RD_A(a[3], 7, 0, buf);                             \
    if ((t) < NT - 1) STAGE(1, (t) + 1, 0, nbuf);                             \
    PHASE_SYNC();                                                             \
    MFMA_Q(4);                                                                \
    /* phase 3: compute (m0-3, k1); stage B(t+1) k1 */                        \
    RD_A(a[0], 0, 1, buf); RD_A(a[1], 1, 1, buf);                             \
    RD_A(a[2], 2, 1, buf); RD_A(a[3], 3, 1, buf);                             \
    RD_B(b[0], 0, 1, buf); RD_B(b[1], 1, 1, buf);                             \
    RD_B(b[2], 2, 1, buf); RD_B(b[3], 3, 1, buf);                             \
    if ((t) < NT - 1) STAGE(1, (t) + 1, 1, nbuf);                             \
    PHASE_SYNC();                                                             \
    MFMA_Q(0);                                                                \
    /* phase 4: compute (m4-7, k1); stage A(t+2) k0 into current buf */       \
    RD_A(a[0], 4, 1, buf); RD_A(a[1], 5, 1, buf);                             \
    RD_A(a[2], 6, 1, buf); RD_A(a[3], 7, 1, buf);                             \
    if ((t) < NT - 2) {                                                       \
        STAGE(0, (t) + 2, 0, buf);                                            \
        asm volatile("s_waitcnt vmcnt(2)" ::: "memory");                      \
    } else if ((t) == NT - 2) {                                               \
        asm volatile("s_waitcnt vmcnt(0)" ::: "memory");                      \
    }                                                                         \
    PHASE_SYNC();                                                             \
    MFMA_Q(4);                                                                \
} while (0)

__global__ __launch_bounds__(512, 2) void gemm_kernel(const u16* __restrict__ Xb,
                                                      const u16* __restrict__ Wb,
                                                      u16* __restrict__ Y,
                                                      float* __restrict__ Psum) {
    __shared__ u16 lds[65536];   // 128 KiB

    const int tid  = threadIdx.x;
    const int lane = tid & 63;
    const int w    = tid >> 6;     // wave 0..7
    const int wm   = w >> 2;       // M-half
    const int wn   = w & 3;        // N-quarter
    const int fr   = lane & 15;
    const int kg   = lane >> 4;

    // XCD-aware 2D mapping: xcd = bid%8 owns col-blocks [xcd*8, xcd*8+8),
    // walks rows with 4-col inner chunks (W panel 2MB L2-resident).
    const int bid = blockIdx.x;            // 0..2047
    const int xcd = bid & 7;
    const int o   = bid >> 3;              // 0..255
    const int cb  = xcd * 8 + (o >> 7) * 4 + (o & 3);  // 0..63
    const int rb  = (o >> 2) & 31;                     // 0..31
    const int brow = rb * 256;
    const int bcol = cb * 256;

    // per-thread staging source (pre-swizzled global, linear LDS dest)
    const int srow   = lane >> 2;                       // 0..15
    const int kchunk = (lane & 3) ^ ((lane >> 3) & 3);  // phys->logical swizzle
    const u16* gA = Xb + (size_t)(brow + srow) * FEAT + kchunk * 8;
    const u16* gB = Wb + (size_t)(bcol + srow) * FEAT + kchunk * 8;

    f32x4 acc[8][4] = {};
    bf16x8 a[4], b[4];

    // prologue: tile 0 fully + A(1)k0; keep 1 half-tile in flight
    STAGE(0, 0, 0, 0);
    STAGE(0, 0, 1, 0);
    STAGE(1, 0, 0, 0);
    STAGE(1, 0, 1, 0);
    STAGE(0, 1, 0, 1);
    asm volatile("s_waitcnt vmcnt(2)" ::: "memory");
    __builtin_amdgcn_s_barrier();

    for (int tt = 0; tt < NT; tt += 2) {
        TILE_BODY(tt, 0, 1);
        TILE_BODY(tt + 1, 1, 0);
    }

    // ---------------- epilogue ----------------
    float* sspart = reinterpret_cast<float*>(lds);   // [256][4]
    const int colbase = bcol + wn * 64 + fr;
#pragma unroll
    for (int mi = 0; mi < 8; ++mi) {
#pragma unroll
        for (int r = 0; r < 4; ++r) {
            const int lrow = wm * 128 + mi * 16 + kg * 4 + r;
            u16* yrow = Y + (size_t)(brow + lrow) * 32768 + colbase;
            float s = 0.f;
#pragma unroll
            for (int nj = 0; nj < 4; ++nj) {
                const float v = acc[mi][nj][r];
                s += v * v;
                yrow[nj * 16] = f32_to_bf16_bits(v);
            }
            s += __shfl_xor(s, 1, 64);
            s += __shfl_xor(s, 2, 64);
            s += __shfl_xor(s, 4, 64);
            s += __shfl_xor(s, 8, 64);
            if (fr == 0) sspart[lrow * 4 + wn] = s;
        }
    }
    __syncthreads();
    if (tid < 256) {
        const float* sp = sspart + tid * 4;
        Psum[(size_t)(brow + tid) * 64 + cb] = sp[0] + sp[1] + sp[2] + sp[3];
    }
}

// Per-row scale: read bf16 y row + 64 partials, write fp32 normalized row
// in-place over the same 64KB row slot (reads drained before writes).
__global__ __launch_bounds__(1024) void scale_kernel(const u16* __restrict__ Y,
                                                     const float* __restrict__ Psum,
                                                     float* __restrict__ out) {
    const int row = blockIdx.x;
    const int tid = threadIdx.x;
    const ushort8* yr = reinterpret_cast<const ushort8*>(Y + (size_t)row * 32768);
    const ushort8 v0 = yr[2 * tid];
    const ushort8 v1 = yr[2 * tid + 1];

    __shared__ float scs;
    if (tid < 64) {
        float s = Psum[(size_t)row * 64 + tid];
        s += __shfl_xor(s, 1, 64);
        s += __shfl_xor(s, 2, 64);
        s += __shfl_xor(s, 4, 64);
        s += __shfl_xor(s, 8, 64);
        s += __shfl_xor(s, 16, 64);
        s += __shfl_xor(s, 32, 64);
        if (tid == 0) scs = rsqrtf(s * (1.0f / (float)NOUT) + EPS);
    }
    // all row loads must have completed before any thread overwrites the row
    asm volatile("s_waitcnt vmcnt(0)" ::: "memory");
    __syncthreads();
    const float sc = scs;

    float4* orow = reinterpret_cast<float4*>(out + (size_t)row * NOUT) + tid * 4;
    float4 o0, o1, o2, o3;
    o0.x = bf16_bits_to_f32(v0[0]) * sc; o0.y = bf16_bits_to_f32(v0[1]) * sc;
    o0.z = bf16_bits_to_f32(v0[2]) * sc; o0.w = bf16_bits_to_f32(v0[3]) * sc;
    o1.x = bf16_bits_to_f32(v0[4]) * sc; o1.y = bf16_bits_to_f32(v0[5]) * sc;
    o1.z = bf16_bits_to_f32(v0[6]) * sc; o1.w = bf16_bits_to_f32(v0[7]) * sc;
    o2.x = bf16_bits_to_f32(v1[0]) * sc; o2.y = bf16_bits_to_f32(v1[1]) * sc;
    o2.z = bf16_bits_to_f32(v1[2]) * sc; o2.w = bf16_bits_to_f32(v1[3]) * sc;
    o3.x = bf16_bits_to_f32(v1[4]) * sc; o3.y = bf16_bits_to_f32(v1[5]) * sc;
    o3.z = bf16_bits_to_f32(v1[6]) * sc; o3.w = bf16_bits_to_f32(v1[7]) * sc;
    orow[0] = o0; orow[1] = o1; orow[2] = o2; orow[3] = o3;
}

extern "C" void kernel_launch(void* const* d_in, const int* in_sizes, int n_in,
                              void* d_out, int out_size, void* d_ws, size_t ws_size,
                              hipStream_t stream) {
    const float* x = (const float*)d_in[0];   // (8192,1024) fp32
    const float* w = (const float*)d_in[1];   // (80,1024) fp32
    float* out = (float*)d_out;               // (8192,16384) fp32

    const int M = in_sizes[0] / FEAT;         // 8192

    u16* Wb = (u16*)d_ws;                                               // 32 MiB
    u16* Xb = (u16*)((char*)d_ws + (size_t)NOUT * FEAT * 2);            // 16 MiB
    float* Psum = (float*)((char*)d_ws + (size_t)(NOUT + M) * FEAT * 2); // 2 MiB

    u16* Y = (u16*)d_out;   // bf16 y in first 32KB of each 64KB out row

    wbuild_kernel<<<(NOUT * (FEAT / 8)) / 256, 256, 0, stream>>>(w, Wb);
    xcast_kernel<<<(M * FEAT / 8) / 256, 256, 0, stream>>>(x, Xb);

    const int nblk = (M / 256) * (NOUT / 256);   // 2048
    gemm_kernel<<<nblk, 512, 0, stream>>>(Xb, Wb, Y, Psum);

    scale_kernel<<<M, 1024, 0, stream>>>(Y, Psum, out);
}

// Round 4
// 481.182 us; speedup vs baseline: 1.4334x; 1.0044x over previous
//
#include <hip/hip_runtime.h>
#include <hip/hip_bf16.h>

typedef unsigned short u16;
typedef __attribute__((ext_vector_type(8))) short bf16x8;
typedef __attribute__((ext_vector_type(4))) float f32x4;
typedef __attribute__((ext_vector_type(8))) unsigned short ushort8;

#define FEAT 1024
#define NOUT 16384
#define EPS 1e-6f
#define NT 16            // K-tiles of 64

#define GLOBAL_AS __attribute__((address_space(1)))
#define LDS_AS __attribute__((address_space(3)))

__device__ __forceinline__ void load16_to_lds(const u16* g, u16* l) {
    __builtin_amdgcn_global_load_lds((const GLOBAL_AS void*)g, (LDS_AS void*)l, 16, 0, 0);
}

__device__ __forceinline__ u16 f32_to_bf16_bits(float f) {
    __hip_bfloat16 h = __float2bfloat16(f);
    return *reinterpret_cast<u16*>(&h);
}

__device__ __forceinline__ float bf16_bits_to_f32(u16 b) {
    unsigned u = ((unsigned)b) << 16;
    float f;
    __builtin_memcpy(&f, &u, 4);
    return f;
}

// Build W[o][k] = A[a][k]*B[b][k]*C[c][k] in bf16, o = a*512 + b*16 + c.
__global__ void wbuild_kernel(const float* __restrict__ w, u16* __restrict__ Wb) {
    const int t  = blockIdx.x * 256 + threadIdx.x;
    const int o  = t >> 7;
    const int k0 = (t & 127) << 3;
    const int ai = o >> 9;
    const int bi = (o >> 4) & 31;
    const int ci = o & 15;
    const float* A = w + ai * FEAT + k0;
    const float* B = w + (32 + bi) * FEAT + k0;
    const float* C = w + (64 + ci) * FEAT + k0;
    ushort8 r;
#pragma unroll
    for (int j = 0; j < 8; ++j) r[j] = f32_to_bf16_bits(A[j] * B[j] * C[j]);
    *reinterpret_cast<ushort8*>(Wb + (size_t)t * 8) = r;
}

__global__ void xcast_kernel(const float* __restrict__ x, u16* __restrict__ Xb) {
    const int t = blockIdx.x * 256 + threadIdx.x;
    const float4* xv = reinterpret_cast<const float4*>(x) + (size_t)t * 2;
    const float4 f0 = xv[0];
    const float4 f1 = xv[1];
    float vals[8] = {f0.x, f0.y, f0.z, f0.w, f1.x, f1.y, f1.z, f1.w};
    ushort8 r;
#pragma unroll
    for (int j = 0; j < 8; ++j) r[j] = f32_to_bf16_bits(vals[j]);
    *reinterpret_cast<ushort8*>(Xb + (size_t)t * 8) = r;
}

// ---------------- 256x256 8-phase deep-pipelined GEMM ----------------
// 512 threads = 8 waves (2 M-halves x 4 N-quarters), wave tile 128x64.
// LDS: 2 buffers x (A 256x64 + B 256x64) bf16 = 128 KiB,
// [buf][op][khalf][256 rows][32 cols], 16B chunks XOR-swizzled.
// Stage rotation during tile t (tile t lives in buf = t&1):
//   p1: (t+1).A k1 -> buf^1     p2: (t+1).B k1 -> buf^1
//   p3: (t+2).A k0 -> buf       p4: (t+2).B k0 -> buf   (k0 dead after p2)
// Every half-tile consumed 4-6 phases after issue. Counted waits BEFORE the
// trailing barrier of p2 (covers this tile's k1) and p4 (covers next k0):
// steady state vmcnt(8) (4 stages = 8 loads in flight), tail vmcnt(4)/(0).

#define LDSOFF(buf, isB, kh) (((buf) << 15) + ((isB) << 14) + ((kh) << 13))

#define STAGE(isB, tt, kh, buf) do {                                          \
    const u16* g = ((isB) ? gB : gA) + (size_t)(tt) * 64 + (kh) * 32 + w * 32768; \
    u16* l = lds + LDSOFF(buf, isB, kh) + w * 1024;                           \
    load16_to_lds(g, l);                                                      \
    load16_to_lds(g + 16384, l + 512);                                        \
} while (0)

#define RD_A(dst, mi, ks, buf) dst = *reinterpret_cast<const bf16x8*>(        \
    lds + LDSOFF(buf, 0, ks) + (wm * 128 + (mi) * 16 + fr) * 32 + ((kg ^ ((fr >> 1) & 3)) << 3))
#define RD_B(dst, nj, ks, buf) dst = *reinterpret_cast<const bf16x8*>(        \
    lds + LDSOFF(buf, 1, ks) + (wn * 64 + (nj) * 16 + fr) * 32 + ((kg ^ ((fr >> 1) & 3)) << 3))

#define PHASE_SYNC() do {                                                     \
    __builtin_amdgcn_sched_barrier(0);                                        \
    __builtin_amdgcn_s_barrier();                                             \
    asm volatile("s_waitcnt lgkmcnt(0)" ::: "memory");                        \
    __builtin_amdgcn_sched_barrier(0);                                        \
} while (0)

// MFMA quadrant; WAITCODE emitted after setprio(0), before trailing barrier.
#define MFMA_Q(mibase, WAITCODE) do {                                         \
    __builtin_amdgcn_s_setprio(1);                                            \
    _Pragma("unroll")                                                         \
    for (int mi = 0; mi < 4; ++mi) {                                          \
        acc[(mibase)+mi][0] = __builtin_amdgcn_mfma_f32_16x16x32_bf16(a[mi], b[0], acc[(mibase)+mi][0], 0, 0, 0); \
        acc[(mibase)+mi][1] = __builtin_amdgcn_mfma_f32_16x16x32_bf16(a[mi], b[1], acc[(mibase)+mi][1], 0, 0, 0); \
        acc[(mibase)+mi][2] = __builtin_amdgcn_mfma_f32_16x16x32_bf16(a[mi], b[2], acc[(mibase)+mi][2], 0, 0, 0); \
        acc[(mibase)+mi][3] = __builtin_amdgcn_mfma_f32_16x16x32_bf16(a[mi], b[3], acc[(mibase)+mi][3], 0, 0, 0); \
    }                                                                         \
    __builtin_amdgcn_s_setprio(0);                                            \
    __builtin_amdgcn_sched_barrier(0);                                        \
    WAITCODE;                                                                 \
    __builtin_amdgcn_sched_barrier(0);                                        \
    __builtin_amdgcn_s_barrier();                                             \
} while (0)

#define NOWAIT ((void)0)
// end of p2: publish this tile's k1 halves (staged at (t-1).p1/p2)
#define WAIT_P2(t) do {                                                       \
    if ((t) == NT - 1) { asm volatile("s_waitcnt vmcnt(0)" ::: "memory"); }   \
    else               { asm volatile("s_waitcnt vmcnt(8)" ::: "memory"); }   \
} while (0)
// end of p4: publish next tile's k0 halves (staged at (t-1).p3/p4)
#define WAIT_P4(t) do {                                                       \
    if ((t) < NT - 2)       { asm volatile("s_waitcnt vmcnt(8)" ::: "memory"); } \
    else if ((t) == NT - 2) { asm volatile("s_waitcnt vmcnt(4)" ::: "memory"); } \
} while (0)

#define TILE_BODY(t, buf, nbuf) do {                                          \
    /* phase 1: compute (m0-3, k0); stage (t+1).A k1 -> nbuf */               \
    RD_A(a[0], 0, 0, buf); RD_A(a[1], 1, 0, buf);                             \
    RD_A(a[2], 2, 0, buf); RD_A(a[3], 3, 0, buf);                             \
    RD_B(b[0], 0, 0, buf); RD_B(b[1], 1, 0, buf);                             \
    RD_B(b[2], 2, 0, buf); RD_B(b[3], 3, 0, buf);                             \
    if ((t) < NT - 1) STAGE(0, (t) + 1, 1, nbuf);                             \
    PHASE_SYNC();                                                             \
    MFMA_Q(0, NOWAIT);                                                        \
    /* phase 2: compute (m4-7, k0); stage (t+1).B k1 -> nbuf */               \
    RD_A(a[0], 4, 0, buf); RD_A(a[1], 5, 0, buf);                             \
    RD_A(a[2], 6, 0, buf); RD_A(a[3], 7, 0, buf);                             \
    if ((t) < NT - 1) STAGE(1, (t) + 1, 1, nbuf);                             \
    PHASE_SYNC();                                                             \
    MFMA_Q(4, WAIT_P2(t));                                                    \
    /* phase 3: compute (m0-3, k1); stage (t+2).A k0 -> buf (k0 dead) */      \
    RD_A(a[0], 0, 1, buf); RD_A(a[1], 1, 1, buf);                             \
    RD_A(a[2], 2, 1, buf); RD_A(a[3], 3, 1, buf);                             \
    RD_B(b[0], 0, 1, buf); RD_B(b[1], 1, 1, buf);                             \
    RD_B(b[2], 2, 1, buf); RD_B(b[3], 3, 1, buf);                             \
    if ((t) < NT - 2) STAGE(0, (t) + 2, 0, buf);                              \
    PHASE_SYNC();                                                             \
    MFMA_Q(0, NOWAIT);                                                        \
    /* phase 4: compute (m4-7, k1); stage (t+2).B k0 -> buf */                \
    RD_A(a[0], 4, 1, buf); RD_A(a[1], 5, 1, buf);                             \
    RD_A(a[2], 6, 1, buf); RD_A(a[3], 7, 1, buf);                             \
    if ((t) < NT - 2) STAGE(1, (t) + 2, 0, buf);                              \
    PHASE_SYNC();                                                             \
    MFMA_Q(4, WAIT_P4(t));                                                    \
} while (0)

__global__ __launch_bounds__(512, 2) void gemm_kernel(const u16* __restrict__ Xb,
                                                      const u16* __restrict__ Wb,
                                                      u16* __restrict__ Y,
                                                      float* __restrict__ Psum) {
    __shared__ u16 lds[65536];   // 128 KiB

    const int tid  = threadIdx.x;
    const int lane = tid & 63;
    const int w    = tid >> 6;     // wave 0..7
    const int wm   = w >> 2;       // M-half
    const int wn   = w & 3;        // N-quarter
    const int fr   = lane & 15;
    const int kg   = lane >> 4;

    // XCD-aware 2D mapping: xcd = bid%8 owns col-blocks [xcd*8, xcd*8+8),
    // walks rows with 4-col inner chunks (W panel 4MB L2-resident).
    const int bid = blockIdx.x;            // 0..2047
    const int xcd = bid & 7;
    const int o   = bid >> 3;              // 0..255
    const int cb  = xcd * 8 + (o >> 7) * 4 + (o & 3);  // 0..63
    const int rb  = (o >> 2) & 31;                     // 0..31
    const int brow = rb * 256;
    const int bcol = cb * 256;

    // per-thread staging source (pre-swizzled global, linear LDS dest)
    const int srow   = lane >> 2;                       // 0..15
    const int kchunk = (lane & 3) ^ ((lane >> 3) & 3);  // phys->logical swizzle
    const u16* gA = Xb + (size_t)(brow + srow) * FEAT + kchunk * 8;
    const u16* gB = Wb + (size_t)(bcol + srow) * FEAT + kchunk * 8;

    f32x4 acc[8][4] = {};
    bf16x8 a[4], b[4];

    // prologue: tile 0 fully (buf0) + tile1 k0 halves (buf1): 6 stages.
    // vmcnt(8) leaves the newest 4 stages in flight; tile0 k0/k1... need
    // only t0.Ak0/Bk0 for p1 -> oldest 2 of 6 done at vmcnt(8).
    STAGE(0, 0, 0, 0);
    STAGE(1, 0, 0, 0);
    STAGE(0, 0, 1, 0);
    STAGE(1, 0, 1, 0);
    STAGE(0, 1, 0, 1);
    STAGE(1, 1, 0, 1);
    asm volatile("s_waitcnt vmcnt(8)" ::: "memory");
    __builtin_amdgcn_s_barrier();

    for (int tt = 0; tt < NT; tt += 2) {
        TILE_BODY(tt, 0, 1);
        TILE_BODY(tt + 1, 1, 0);
    }

    // ---------------- epilogue ----------------
    float* sspart = reinterpret_cast<float*>(lds);   // [256][4]
    const int colbase = bcol + wn * 64 + fr;
#pragma unroll
    for (int mi = 0; mi < 8; ++mi) {
#pragma unroll
        for (int r = 0; r < 4; ++r) {
            const int lrow = wm * 128 + mi * 16 + kg * 4 + r;
            u16* yrow = Y + (size_t)(brow + lrow) * 32768 + colbase;
            float s = 0.f;
#pragma unroll
            for (int nj = 0; nj < 4; ++nj) {
                const float v = acc[mi][nj][r];
                s += v * v;
                yrow[nj * 16] = f32_to_bf16_bits(v);
            }
            s += __shfl_xor(s, 1, 64);
            s += __shfl_xor(s, 2, 64);
            s += __shfl_xor(s, 4, 64);
            s += __shfl_xor(s, 8, 64);
            if (fr == 0) sspart[lrow * 4 + wn] = s;
        }
    }
    __syncthreads();
    if (tid < 256) {
        const float* sp = sspart + tid * 4;
        Psum[(size_t)(brow + tid) * 64 + cb] = sp[0] + sp[1] + sp[2] + sp[3];
    }
}

// Per-row scale: read bf16 y row + 64 partials, write fp32 normalized row
// in-place over the same 64KB row slot (reads drained before writes).
__global__ __launch_bounds__(1024) void scale_kernel(const u16* __restrict__ Y,
                                                     const float* __restrict__ Psum,
                                                     float* __restrict__ out) {
    const int row = blockIdx.x;
    const int tid = threadIdx.x;
    const ushort8* yr = reinterpret_cast<const ushort8*>(Y + (size_t)row * 32768);
    const ushort8 v0 = yr[2 * tid];
    const ushort8 v1 = yr[2 * tid + 1];

    __shared__ float scs;
    if (tid < 64) {
        float s = Psum[(size_t)row * 64 + tid];
        s += __shfl_xor(s, 1, 64);
        s += __shfl_xor(s, 2, 64);
        s += __shfl_xor(s, 4, 64);
        s += __shfl_xor(s, 8, 64);
        s += __shfl_xor(s, 16, 64);
        s += __shfl_xor(s, 32, 64);
        if (tid == 0) scs = rsqrtf(s * (1.0f / (float)NOUT) + EPS);
    }
    // all row loads must have completed before any thread overwrites the row
    asm volatile("s_waitcnt vmcnt(0)" ::: "memory");
    __syncthreads();
    const float sc = scs;

    float4* orow = reinterpret_cast<float4*>(out + (size_t)row * NOUT) + tid * 4;
    float4 o0, o1, o2, o3;
    o0.x = bf16_bits_to_f32(v0[0]) * sc; o0.y = bf16_bits_to_f32(v0[1]) * sc;
    o0.z = bf16_bits_to_f32(v0[2]) * sc; o0.w = bf16_bits_to_f32(v0[3]) * sc;
    o1.x = bf16_bits_to_f32(v0[4]) * sc; o1.y = bf16_bits_to_f32(v0[5]) * sc;
    o1.z = bf16_bits_to_f32(v0[6]) * sc; o1.w = bf16_bits_to_f32(v0[7]) * sc;
    o2.x = bf16_bits_to_f32(v1[0]) * sc; o2.y = bf16_bits_to_f32(v1[1]) * sc;
    o2.z = bf16_bits_to_f32(v1[2]) * sc; o2.w = bf16_bits_to_f32(v1[3]) * sc;
    o3.x = bf16_bits_to_f32(v1[4]) * sc; o3.y = bf16_bits_to_f32(v1[5]) * sc;
    o3.z = bf16_bits_to_f32(v1[6]) * sc; o3.w = bf16_bits_to_f32(v1[7]) * sc;
    orow[0] = o0; orow[1] = o1; orow[2] = o2; orow[3] = o3;
}

extern "C" void kernel_launch(void* const* d_in, const int* in_sizes, int n_in,
                              void* d_out, int out_size, void* d_ws, size_t ws_size,
                              hipStream_t stream) {
    const float* x = (const float*)d_in[0];   // (8192,1024) fp32
    const float* w = (const float*)d_in[1];   // (80,1024) fp32
    float* out = (float*)d_out;               // (8192,16384) fp32

    const int M = in_sizes[0] / FEAT;         // 8192

    u16* Wb = (u16*)d_ws;                                               // 32 MiB
    u16* Xb = (u16*)((char*)d_ws + (size_t)NOUT * FEAT * 2);            // 16 MiB
    float* Psum = (float*)((char*)d_ws + (size_t)(NOUT + M) * FEAT * 2); // 2 MiB

    u16* Y = (u16*)d_out;   // bf16 y in first 32KB of each 64KB out row

    wbuild_kernel<<<(NOUT * (FEAT / 8)) / 256, 256, 0, stream>>>(w, Wb);
    xcast_kernel<<<(M * FEAT / 8) / 256, 256, 0, stream>>>(x, Xb);

    const int nblk = (M / 256) * (NOUT / 256);   // 2048
    gemm_kernel<<<nblk, 512, 0, stream>>>(Xb, Wb, Y, Psum);

    scale_kernel<<<M, 1024, 0, stream>>>(Y, Psum, out);
}

// Round 5
// 451.650 us; speedup vs baseline: 1.5271x; 1.0654x over previous
//
#include <hip/hip_runtime.h>
#include <hip/hip_bf16.h>

typedef unsigned short u16;
typedef __attribute__((ext_vector_type(8))) short bf16x8;
typedef __attribute__((ext_vector_type(4))) float f32x4;
typedef __attribute__((ext_vector_type(8))) unsigned short ushort8;

#define FEAT 1024
#define NOUT 16384
#define EPS 1e-6f
#define NT 16            // K-tiles of 64

#define GLOBAL_AS __attribute__((address_space(1)))
#define LDS_AS __attribute__((address_space(3)))

__device__ __forceinline__ void load16_to_lds(const u16* g, u16* l) {
    __builtin_amdgcn_global_load_lds((const GLOBAL_AS void*)g, (LDS_AS void*)l, 16, 0, 0);
}

__device__ __forceinline__ u16 f32_to_bf16_bits(float f) {
    __hip_bfloat16 h = __float2bfloat16(f);
    return *reinterpret_cast<u16*>(&h);
}

__device__ __forceinline__ float bf16_bits_to_f32(u16 b) {
    unsigned u = ((unsigned)b) << 16;
    float f;
    __builtin_memcpy(&f, &u, 4);
    return f;
}

// Build Wb with a baked-in within-64-row permutation:
//   Wb[p] = W_row[ (p & ~63) | ((p&15)<<2) | ((p>>4)&3) ]
// so that the GEMM epilogue's fragment (nj, fr) maps to 4 CONTIGUOUS output
// columns fr*4+nj (coalesced 8B packed stores). W_row o = A[o>>9]*B[(o>>4)&31]*C[o&15].
__global__ void wbuild_kernel(const float* __restrict__ w, u16* __restrict__ Wb) {
    const int t  = blockIdx.x * 256 + threadIdx.x;
    const int p  = t >> 7;                      // Wb row (permuted position)
    const int k0 = (t & 127) << 3;
    const int o  = (p & ~63) | ((p & 15) << 2) | ((p >> 4) & 3);  // logical W row
    const int ai = o >> 9;
    const int bi = (o >> 4) & 31;
    const int ci = o & 15;
    const float* A = w + ai * FEAT + k0;
    const float* B = w + (32 + bi) * FEAT + k0;
    const float* C = w + (64 + ci) * FEAT + k0;
    ushort8 r;
#pragma unroll
    for (int j = 0; j < 8; ++j) r[j] = f32_to_bf16_bits(A[j] * B[j] * C[j]);
    *reinterpret_cast<ushort8*>(Wb + (size_t)t * 8) = r;
}

__global__ void xcast_kernel(const float* __restrict__ x, u16* __restrict__ Xb) {
    const int t = blockIdx.x * 256 + threadIdx.x;
    const float4* xv = reinterpret_cast<const float4*>(x) + (size_t)t * 2;
    const float4 f0 = xv[0];
    const float4 f1 = xv[1];
    float vals[8] = {f0.x, f0.y, f0.z, f0.w, f1.x, f1.y, f1.z, f1.w};
    ushort8 r;
#pragma unroll
    for (int j = 0; j < 8; ++j) r[j] = f32_to_bf16_bits(vals[j]);
    *reinterpret_cast<ushort8*>(Xb + (size_t)t * 8) = r;
}

// ---------------- 256x256 pipelined GEMM, 2 barriers/K-tile ----------------
// 512 threads = 8 waves (2 M-halves x 4 N-quarters), wave tile 128x64.
// LDS: 2 buffers x (A 256x64 + B 256x64) bf16 = 128 KiB,
// [buf][op][khalf][256 rows][32 cols], 16B chunks XOR-swizzled via global src.
// Per tile t (lives in buf = t&1), two halves:
//  half k0: reads k0 frags + MFMA; stages (t+1).Ak1, (t+1).Bk1 -> nbuf;
//           vmcnt(8) publishes THIS tile's k1 (staged t-1); barrier.
//  half k1: reads k1 frags + MFMA; stages (t+2).Ak0, (t+2).Bk0 -> buf
//           (k0 regions dead: consumed before previous barrier);
//           vmcnt(8) publishes NEXT tile's k0 (staged t-1); barrier.
// No lgkmcnt(0)/mid-barrier: ds_read->MFMA ordering is data-dependence
// (compiler emits counted lgkmcnt; LDS pipe drains under MFMA). Every read
// is consumed by this half's MFMAs, so the half-end barrier alone excludes
// cross-wave WAR on staged regions.

#define LDSOFF(buf, isB, kh) (((buf) << 15) + ((isB) << 14) + ((kh) << 13))

#define STAGE(isB, tt, kh, buf) do {                                          \
    const u16* g = ((isB) ? gB : gA) + (size_t)(tt) * 64 + (kh) * 32 + w * 32768; \
    u16* l = lds + LDSOFF(buf, isB, kh) + w * 1024;                           \
    load16_to_lds(g, l);                                                      \
    load16_to_lds(g + 16384, l + 512);                                        \
} while (0)

#define RD_A(dst, mi, ks, buf) dst = *reinterpret_cast<const bf16x8*>(        \
    lds + LDSOFF(buf, 0, ks) + (wm * 128 + (mi) * 16 + fr) * 32 + ((kg ^ ((fr >> 1) & 3)) << 3))
#define RD_B(dst, nj, ks, buf) dst = *reinterpret_cast<const bf16x8*>(        \
    lds + LDSOFF(buf, 1, ks) + (wn * 64 + (nj) * 16 + fr) * 32 + ((kg ^ ((fr >> 1) & 3)) << 3))

#define BAR() do {                                                            \
    __builtin_amdgcn_sched_barrier(0);                                        \
    __builtin_amdgcn_s_barrier();                                             \
    __builtin_amdgcn_sched_barrier(0);                                        \
} while (0)

#define MFMAQ(mibase) do {                                                    \
    __builtin_amdgcn_s_setprio(1);                                            \
    _Pragma("unroll")                                                         \
    for (int mi = 0; mi < 4; ++mi) {                                          \
        acc[(mibase)+mi][0] = __builtin_amdgcn_mfma_f32_16x16x32_bf16(a[mi], b[0], acc[(mibase)+mi][0], 0, 0, 0); \
        acc[(mibase)+mi][1] = __builtin_amdgcn_mfma_f32_16x16x32_bf16(a[mi], b[1], acc[(mibase)+mi][1], 0, 0, 0); \
        acc[(mibase)+mi][2] = __builtin_amdgcn_mfma_f32_16x16x32_bf16(a[mi], b[2], acc[(mibase)+mi][2], 0, 0, 0); \
        acc[(mibase)+mi][3] = __builtin_amdgcn_mfma_f32_16x16x32_bf16(a[mi], b[3], acc[(mibase)+mi][3], 0, 0, 0); \
    }                                                                         \
    __builtin_amdgcn_s_setprio(0);                                            \
} while (0)

// half-end counted waits (loads are 2 per STAGE; 8 = 4 stages in flight)
#define WAIT_H1(t) do {                                                       \
    if ((t) == NT - 1) { asm volatile("s_waitcnt vmcnt(0)" ::: "memory"); }   \
    else               { asm volatile("s_waitcnt vmcnt(8)" ::: "memory"); }   \
} while (0)
#define WAIT_H2(t) do {                                                       \
    if ((t) < NT - 2)       { asm volatile("s_waitcnt vmcnt(8)" ::: "memory"); } \
    else if ((t) == NT - 2) { asm volatile("s_waitcnt vmcnt(4)" ::: "memory"); } \
} while (0)

#define HALF(kh, buf, doStage, stT, stKh, stBuf, WAITC) do {                  \
    RD_A(a[0], 0, kh, buf); RD_A(a[1], 1, kh, buf);                           \
    RD_A(a[2], 2, kh, buf); RD_A(a[3], 3, kh, buf);                           \
    RD_B(b[0], 0, kh, buf); RD_B(b[1], 1, kh, buf);                           \
    RD_B(b[2], 2, kh, buf); RD_B(b[3], 3, kh, buf);                           \
    if (doStage) STAGE(0, stT, stKh, stBuf);                                  \
    MFMAQ(0);                                                                 \
    RD_A(a[0], 4, kh, buf); RD_A(a[1], 5, kh, buf);                           \
    RD_A(a[2], 6, kh, buf); RD_A(a[3], 7, kh, buf);                           \
    if (doStage) STAGE(1, stT, stKh, stBuf);                                  \
    MFMAQ(4);                                                                 \
    WAITC;                                                                    \
    BAR();                                                                    \
} while (0)

#define TILE_BODY(t, buf, nbuf) do {                                          \
    HALF(0, buf, (t) < NT - 1, (t) + 1, 1, nbuf, WAIT_H1(t));                 \
    HALF(1, buf, (t) < NT - 2, (t) + 2, 0, buf,  WAIT_H2(t));                 \
} while (0)

__global__ __launch_bounds__(512, 2) void gemm_kernel(const u16* __restrict__ Xb,
                                                      const u16* __restrict__ Wb,
                                                      u16* __restrict__ Y) {
    __shared__ u16 lds[65536];   // 128 KiB

    const int tid  = threadIdx.x;
    const int lane = tid & 63;
    const int w    = tid >> 6;     // wave 0..7
    const int wm   = w >> 2;       // M-half
    const int wn   = w & 3;        // N-quarter
    const int fr   = lane & 15;
    const int kg   = lane >> 4;

    // XCD-aware 2D mapping: xcd = bid%8 owns col-blocks [xcd*8, xcd*8+8),
    // walks rows with 4-col inner chunks (W panel 4MB L2-resident).
    const int bid = blockIdx.x;            // 0..2047
    const int xcd = bid & 7;
    const int o   = bid >> 3;              // 0..255
    const int cb  = xcd * 8 + (o >> 7) * 4 + (o & 3);  // 0..63
    const int rb  = (o >> 2) & 31;                     // 0..31
    const int brow = rb * 256;
    const int bcol = cb * 256;

    // per-thread staging source (pre-swizzled global, linear LDS dest)
    const int srow   = lane >> 2;                       // 0..15
    const int kchunk = (lane & 3) ^ ((lane >> 3) & 3);  // phys->logical swizzle
    const u16* gA = Xb + (size_t)(brow + srow) * FEAT + kchunk * 8;
    const u16* gB = Wb + (size_t)(bcol + srow) * FEAT + kchunk * 8;

    f32x4 acc[8][4] = {};
    bf16x8 a[4], b[4];

    // prologue: tile 0 fully (buf0) + tile1 k0 halves (buf1) = 12 loads;
    // vmcnt(8) -> oldest 4 (t0.Ak0 + t0.Bk0) landed before first reads.
    STAGE(0, 0, 0, 0);
    STAGE(1, 0, 0, 0);
    STAGE(0, 0, 1, 0);
    STAGE(1, 0, 1, 0);
    STAGE(0, 1, 0, 1);
    STAGE(1, 1, 0, 1);
    asm volatile("s_waitcnt vmcnt(8)" ::: "memory");
    BAR();

    for (int tt = 0; tt < NT; tt += 2) {
        TILE_BODY(tt, 0, 1);
        TILE_BODY(tt + 1, 1, 0);
    }

    // ---------------- epilogue: packed coalesced bf16 stores ----------------
    // fragment (nj, fr) = output col bcol + wn*64 + fr*4 + nj (B permuted in wbuild)
    const int colbase = bcol + wn * 64 + fr * 4;
#pragma unroll
    for (int mi = 0; mi < 8; ++mi) {
#pragma unroll
        for (int r = 0; r < 4; ++r) {
            const int row = brow + wm * 128 + mi * 16 + kg * 4 + r;
            const unsigned lo = (unsigned)f32_to_bf16_bits(acc[mi][0][r]) |
                                ((unsigned)f32_to_bf16_bits(acc[mi][1][r]) << 16);
            const unsigned hi = (unsigned)f32_to_bf16_bits(acc[mi][2][r]) |
                                ((unsigned)f32_to_bf16_bits(acc[mi][3][r]) << 16);
            uint2 pk; pk.x = lo; pk.y = hi;
            *reinterpret_cast<uint2*>(Y + (size_t)row * 32768 + colbase) = pk;
        }
    }
}

// Per-row scale: read bf16 y row, compute sum-of-squares from it (bf16-
// quantized ss: rel err <=0.4%, far under threshold), write fp32 normalized
// row in-place over the same 64KB row slot. Cross-thread WAR is ordered by
// the __syncthreads (every thread's loads are consumed into ss before it).
__global__ __launch_bounds__(1024) void scale_kernel(const u16* __restrict__ Y,
                                                     float* __restrict__ out) {
    const int row = blockIdx.x;
    const int tid = threadIdx.x;
    const ushort8* yr = reinterpret_cast<const ushort8*>(Y + (size_t)row * 32768);
    const ushort8 v0 = yr[2 * tid];
    const ushort8 v1 = yr[2 * tid + 1];

    float f[16];
#pragma unroll
    for (int j = 0; j < 8; ++j) {
        f[j]     = bf16_bits_to_f32(v0[j]);
        f[8 + j] = bf16_bits_to_f32(v1[j]);
    }
    float ss = 0.f;
#pragma unroll
    for (int j = 0; j < 16; ++j) ss += f[j] * f[j];

#pragma unroll
    for (int off = 1; off < 64; off <<= 1) ss += __shfl_xor(ss, off, 64);
    __shared__ float wss[16];
    if ((tid & 63) == 0) wss[tid >> 6] = ss;
    __syncthreads();
    float tot = 0.f;
#pragma unroll
    for (int i = 0; i < 16; ++i) tot += wss[i];
    const float sc = rsqrtf(tot * (1.0f / (float)NOUT) + EPS);

    float4* orow = reinterpret_cast<float4*>(out + (size_t)row * NOUT) + tid * 4;
#pragma unroll
    for (int q = 0; q < 4; ++q) {
        float4 ov;
        ov.x = f[q * 4 + 0] * sc;
        ov.y = f[q * 4 + 1] * sc;
        ov.z = f[q * 4 + 2] * sc;
        ov.w = f[q * 4 + 3] * sc;
        orow[q] = ov;
    }
}

extern "C" void kernel_launch(void* const* d_in, const int* in_sizes, int n_in,
                              void* d_out, int out_size, void* d_ws, size_t ws_size,
                              hipStream_t stream) {
    const float* x = (const float*)d_in[0];   // (8192,1024) fp32
    const float* w = (const float*)d_in[1];   // (80,1024) fp32
    float* out = (float*)d_out;               // (8192,16384) fp32

    const int M = in_sizes[0] / FEAT;         // 8192

    u16* Wb = (u16*)d_ws;                                      // 32 MiB
    u16* Xb = (u16*)((char*)d_ws + (size_t)NOUT * FEAT * 2);   // 16 MiB

    u16* Y = (u16*)d_out;   // bf16 y in first 32KB of each 64KB out row

    wbuild_kernel<<<(NOUT * (FEAT / 8)) / 256, 256, 0, stream>>>(w, Wb);
    xcast_kernel<<<(M * FEAT / 8) / 256, 256, 0, stream>>>(x, Xb);

    const int nblk = (M / 256) * (NOUT / 256);   // 2048
    gemm_kernel<<<nblk, 512, 0, stream>>>(Xb, Wb, Y);

    scale_kernel<<<M, 1024, 0, stream>>>(Y, out);
}